// Round 7
// baseline (61.473 us; speedup 1.0000x reference)
//
#include <hip/hip_runtime.h>
#include <stdint.h>

// MPS amplitude via MFMA, round 7.
// Pre-kernel converts bulk (62 sites x 2 spins) to bf16 hi/lo B-fragments in
// d_ws (16KB/site, 992KB, L2-resident). Main kernel: 256 blocks x 256 threads
// (4 waves = nt x sw). Each wave computes BOTH element halves (mt=0,1) of its
// spin's 32x16 tile -> 24 MFMAs/site/wave, reusing ONE set of B fragments
// (halves L2 B-traffic vs R6's 8-wave layout where mt-pairs read duplicate B).
// v lives in LDS q-permuted as packed bf16 hi/lo (ds_read_b128 fragments),
// ping-pong buffered; lgkm-only barriers; B register-prefetched 1 site ahead.

typedef __attribute__((ext_vector_type(4))) float        f32x4;
typedef __attribute__((ext_vector_type(8))) short        s16x8;
typedef __attribute__((ext_vector_type(4))) unsigned int u32x4;

__device__ __forceinline__ unsigned cvt_pk_bf16(float lo, float hi) {
    unsigned r;
    asm("v_cvt_pk_bf16_f32 %0, %1, %2" : "=v"(r) : "v"(lo), "v"(hi));
    return r;
}
__device__ __forceinline__ float lo_f(unsigned h) { return __uint_as_float(h << 16); }
__device__ __forceinline__ float hi_f(unsigned h) { return __uint_as_float(h & 0xFFFF0000u); }
__device__ __forceinline__ s16x8 frg(u32x4 x) { return __builtin_bit_cast(s16x8, x); }
#define MFMA16(A, B, C) __builtin_amdgcn_mfma_f32_16x16x32_bf16(frg(A), frg(B), C, 0, 0, 0)

// storage permutation: word u (complex col, K-pair) -> contiguous frag slots
__device__ __forceinline__ int qperm(int u) {
    return (u >> 4) * 16 + ((u >> 1) & 3) * 4 + ((u >> 3) & 1) * 2 + (u & 1);
}

// ws layout (u32 units), per site (stride 4096):
//   off = hl*2048 + s*1024 + kk*512 + g*128 + col*4 + q     (q = 0..3)
__global__ __launch_bounds__(256, 1) void mps_preconvert(
    const float* __restrict__ bulk_r, const float* __restrict__ bulk_i,
    unsigned* __restrict__ ws)
{
    const int site = blockIdx.x;          // 0..61
    const int tid  = threadIdx.x;
    const int ccol = tid & 31;
    const int c0   = tid >> 5;
    const float* br = bulk_r + (size_t)site * 2048 + ccol;
    const float* bi = bulk_i + (size_t)site * 2048 + ccol;
    unsigned* wsu = ws + (size_t)site * 4096;
    #pragma unroll
    for (int h = 0; h < 2; ++h) {
        const int c  = c0 + h * 8;
        const int s  = c >> 3;
        const int kk = (c >> 2) & 1;
        const int g  = c & 3;
        const int ub = kk * 16 + 2 * g;
        const float* R = br + s * 1024;
        const float* I = bi + s * 1024;
        float v0 = R[(ub + 0) * 32], v1 = I[(ub + 0) * 32];
        float v2 = R[(ub + 1) * 32], v3 = I[(ub + 1) * 32];
        float v4 = R[(ub + 8) * 32], v5 = I[(ub + 8) * 32];
        float v6 = R[(ub + 9) * 32], v7 = I[(ub + 9) * 32];
        unsigned h0 = cvt_pk_bf16(v0, v1), h1 = cvt_pk_bf16(v2, v3);
        unsigned h2 = cvt_pk_bf16(v4, v5), h3 = cvt_pk_bf16(v6, v7);
        unsigned l0 = cvt_pk_bf16(v0 - lo_f(h0), v1 - hi_f(h0));
        unsigned l1 = cvt_pk_bf16(v2 - lo_f(h1), v3 - hi_f(h1));
        unsigned l2 = cvt_pk_bf16(v4 - lo_f(h2), v5 - hi_f(h2));
        unsigned l3 = cvt_pk_bf16(v6 - lo_f(h3), v7 - hi_f(h3));
        const unsigned base = (unsigned)(s * 1024 + kk * 512 + g * 128 + ccol * 4);
        *(u32x4*)(wsu + base)        = (u32x4){h0, h1, h2, h3};
        *(u32x4*)(wsu + 2048 + base) = (u32x4){l0, l1, l2, l3};
    }
}

__global__ __launch_bounds__(256, 1) void mps_mfma3_kernel(
    const int*   __restrict__ spin,
    const float* __restrict__ left_r,  const float* __restrict__ left_i,
    const float* __restrict__ right_r, const float* __restrict__ right_i,
    const unsigned* __restrict__ ws,
    float2*      __restrict__ out)
{
    __shared__ unsigned Vst[2][32 * 68];   // [buf][e*68 + {q hi, 32+q lo}]
    __shared__ float2 red[32][8];
    __shared__ unsigned smask[32][2];

    const int tid  = threadIdx.x;
    const int l    = tid & 63;
    const int wid  = tid >> 6;            // 0..3
    const int nt   = wid >> 1;            // column half
    const int sw   = wid & 1;             // spin this wave computes
    const int lr16 = l & 15;
    const int lg   = l >> 4;
    const int jc   = nt * 16 + lr16;      // C column
    const int qjc  = qperm(jc);           // storage slot for column jc
    const int blk  = blockIdx.x;

    // ---- spin masks ----
    if (tid < 32) {
        const int* sp = spin + ((size_t)(blk * 32 + tid)) * 64;
        unsigned a0 = 0, a1 = 0;
        #pragma unroll
        for (int k = 0; k < 32; ++k) a0 |= (unsigned)(sp[k] & 1) << k;
        #pragma unroll
        for (int k = 0; k < 32; ++k) a1 |= (unsigned)(sp[32 + k] & 1) << k;
        smask[tid][0] = a0; smask[tid][1] = a1;
    }

    // ---- init v = left[s0] as packed hi/lo (q-permuted) ----
    {
        const int e  = tid & 31;
        const int j0 = (tid >> 5) * 4;    // 0..28
        const int s0 = spin[((size_t)(blk * 32 + e)) * 64] & 1;
        #pragma unroll
        for (int d = 0; d < 4; ++d) {
            const int j = j0 + d;
            const int qj = qperm(j);
            const float vr = left_r[s0 * 32 + j], vi = left_i[s0 * 32 + j];
            const unsigned h  = cvt_pk_bf16(vr, vi);
            const unsigned lo = cvt_pk_bf16(vr - lo_f(h), vi - hi_f(h));
            Vst[0][e * 68 + qj]      = h;
            Vst[0][e * 68 + 32 + qj] = lo;
        }
    }

    // ---- issue site-0 B-fragment loads ----
    const unsigned* pb0 = ws + sw * 1024 + lg * 128 + jc * 4;
    u32x4 Ah0 = *(const u32x4*)(pb0);
    u32x4 Ah1 = *(const u32x4*)(pb0 + 512);
    u32x4 Al0 = *(const u32x4*)(pb0 + 2048);
    u32x4 Al1 = *(const u32x4*)(pb0 + 2560);
    u32x4 Bh0, Bh1, Bl0, Bl1;

    asm volatile("s_waitcnt lgkmcnt(0)" ::: "memory");
    __builtin_amdgcn_s_barrier();
    __builtin_amdgcn_sched_barrier(0);

    // per-lane spin words for its 8 C-row elements (2 mt x 4 r)
    unsigned em0[8], em1[8];
    #pragma unroll
    for (int mt = 0; mt < 2; ++mt)
        #pragma unroll
        for (int r = 0; r < 4; ++r) {
            const int ee = mt * 16 + lg * 4 + r;
            em0[mt * 4 + r] = smask[ee][0];
            em1[mt * 4 + r] = smask[ee][1];
        }

    auto site = [&](int t, const unsigned* Vin, unsigned* Vout,
                    const u32x4& Ph0, const u32x4& Ph1,
                    const u32x4& Pl0, const u32x4& Pl1,
                    u32x4& Nh0, u32x4& Nh1, u32x4& Nl0, u32x4& Nl1) {
        // prefetch next site's B fragments (in flight across the barrier)
        {
            int tn = t + 1; if (tn > 61) tn = 61;
            const unsigned* pb = ws + (size_t)tn * 4096 + sw * 1024 + lg * 128 + jc * 4;
            Nh0 = *(const u32x4*)(pb);
            Nh1 = *(const u32x4*)(pb + 512);
            Nl0 = *(const u32x4*)(pb + 2048);
            Nl1 = *(const u32x4*)(pb + 2560);
        }

        // one 16x16 tile: derive V_r/V_i for both split terms, 12 MFMAs
        auto tile = [&](const u32x4& Vh0, const u32x4& Vh1,
                        const u32x4& Vl0, const u32x4& Vl1,
                        f32x4& arO, f32x4& aiO) {
            u32x4 r_h0, r_h1, r_l0, r_l1, i_h0, i_h1, i_l0, i_l1;
            #pragma unroll
            for (int q = 0; q < 4; ++q) {
                r_h0[q] = Vh0[q] ^ 0x80000000u;
                r_h1[q] = Vh1[q] ^ 0x80000000u;
                r_l0[q] = Vl0[q] ^ 0x80000000u;
                r_l1[q] = Vl1[q] ^ 0x80000000u;
                i_h0[q] = __builtin_amdgcn_alignbit(Vh0[q], Vh0[q], 16);
                i_h1[q] = __builtin_amdgcn_alignbit(Vh1[q], Vh1[q], 16);
                i_l0[q] = __builtin_amdgcn_alignbit(Vl0[q], Vl0[q], 16);
                i_l1[q] = __builtin_amdgcn_alignbit(Vl1[q], Vl1[q], 16);
            }
            f32x4 arA = {0.f,0.f,0.f,0.f}, arB = {0.f,0.f,0.f,0.f};
            f32x4 aiA = {0.f,0.f,0.f,0.f}, aiB = {0.f,0.f,0.f,0.f};
            arA = MFMA16(r_h0, Ph0, arA); arA = MFMA16(r_h0, Pl0, arA); arA = MFMA16(r_l0, Ph0, arA);
            arB = MFMA16(r_h1, Ph1, arB); arB = MFMA16(r_h1, Pl1, arB); arB = MFMA16(r_l1, Ph1, arB);
            aiA = MFMA16(i_h0, Ph0, aiA); aiA = MFMA16(i_h0, Pl0, aiA); aiA = MFMA16(i_l0, Ph0, aiA);
            aiB = MFMA16(i_h1, Ph1, aiB); aiB = MFMA16(i_h1, Pl1, aiB); aiB = MFMA16(i_l1, Ph1, aiB);
            arO = arA + arB;
            aiO = aiA + aiB;
        };

        // V fragment reads for both element halves (8 x ds_read_b128)
        const unsigned* pv0 = Vin + lr16 * 68 + 4 * lg;
        const unsigned* pv1 = pv0 + 16 * 68;
        u32x4 V0h0 = *(const u32x4*)(pv0);
        u32x4 V0h1 = *(const u32x4*)(pv0 + 16);
        u32x4 V0l0 = *(const u32x4*)(pv0 + 32);
        u32x4 V0l1 = *(const u32x4*)(pv0 + 48);
        u32x4 V1h0 = *(const u32x4*)(pv1);
        u32x4 V1h1 = *(const u32x4*)(pv1 + 16);
        u32x4 V1l0 = *(const u32x4*)(pv1 + 32);
        u32x4 V1l1 = *(const u32x4*)(pv1 + 48);

        f32x4 ar0, ai0, ar1, ai1;
        tile(V0h0, V0h1, V0l0, V0l1, ar0, ai0);
        tile(V1h0, V1h1, V1l0, V1l1, ar1, ai1);

        // winning spin-wave packs and writes v_next (q-permuted)
        const int bp = t + 1;
        #pragma unroll
        for (int mt = 0; mt < 2; ++mt) {
            const f32x4& ar = mt ? ar1 : ar0;
            const f32x4& ai = mt ? ai1 : ai0;
            #pragma unroll
            for (int r = 0; r < 4; ++r) {
                const unsigned mw = (bp < 32) ? em0[mt * 4 + r] : em1[mt * 4 + r];
                const int sb = (int)((mw >> (bp & 31)) & 1u);
                if (sb == sw) {
                    const int ee = mt * 16 + lg * 4 + r;
                    const unsigned h  = cvt_pk_bf16(ar[r], ai[r]);
                    const unsigned lo = cvt_pk_bf16(ar[r] - lo_f(h), ai[r] - hi_f(h));
                    Vout[ee * 68 + qjc]      = h;
                    Vout[ee * 68 + 32 + qjc] = lo;
                }
            }
        }

        // lgkm-only barrier: v exchange visible; B prefetch stays in flight
        asm volatile("s_waitcnt lgkmcnt(0)" ::: "memory");
        __builtin_amdgcn_s_barrier();
        __builtin_amdgcn_sched_barrier(0);
    };

    #pragma unroll 1
    for (int tt = 0; tt < 31; ++tt) {
        site(2 * tt,     Vst[0], Vst[1], Ah0, Ah1, Al0, Al1, Bh0, Bh1, Bl0, Bl1);
        site(2 * tt + 1, Vst[1], Vst[0], Bh0, Bh1, Bl0, Bl1, Ah0, Ah1, Al0, Al1);
    }

    // ---- right contraction ----
    {
        const int e = tid & 31, jg = tid >> 5;
        const unsigned sR = (smask[e][1] >> 31) & 1u;
        const float* Rr = right_r + sR * 32;
        const float* Ri = right_i + sR * 32;
        float pr = 0.f, pi = 0.f;
        #pragma unroll
        for (int d = 0; d < 4; ++d) {
            const int j = jg * 4 + d;
            const int qj = qperm(j);
            const unsigned h  = Vst[0][e * 68 + qj];
            const unsigned lo = Vst[0][e * 68 + 32 + qj];
            const float vr = lo_f(h) + lo_f(lo);
            const float vi = hi_f(h) + hi_f(lo);
            pr += vr * Rr[j] - vi * Ri[j];
            pi += vr * Ri[j] + vi * Rr[j];
        }
        red[e][jg] = make_float2(pr, pi);
    }
    __syncthreads();
    if (tid < 32) {
        float2 a = red[tid][0];
        #pragma unroll
        for (int k = 1; k < 8; ++k) { a.x += red[tid][k].x; a.y += red[tid][k].y; }
        out[blk * 32 + tid] = a;
    }
}

// ---------------- fallback (round-4 kernel) if ws too small ----------------
typedef __attribute__((ext_vector_type(2))) unsigned int u32x2;
__global__ __launch_bounds__(256, 1) void mps_mfma_kernel_fb(
    const int*   __restrict__ spin,
    const float* __restrict__ left_r,  const float* __restrict__ left_i,
    const float* __restrict__ bulk_r,  const float* __restrict__ bulk_i,
    const float* __restrict__ right_r, const float* __restrict__ right_i,
    float2*      __restrict__ out)
{
    __shared__ unsigned short Bf[2][2][2][2][4][32][8];
    __shared__ float vT[2][64][33];
    __shared__ float2 red[32][8];
    __shared__ unsigned smask[32][2];

    const int tid  = threadIdx.x;
    const int l    = tid & 63;
    const int wid  = tid >> 6;
    const int mt   = wid >> 1;
    const int nt   = wid & 1;
    const int lr16 = l & 15;
    const int lg   = l >> 4;
    const int ve   = mt * 16 + lr16;
    const int jc   = nt * 16 + lr16;
    const int blk  = blockIdx.x;
    const int ccol = tid & 31;
    const int c0   = tid >> 5;

    auto convert = [&](int site, int buf) {
        const float* br = bulk_r + (size_t)site * 2048 + ccol;
        const float* bi = bulk_i + (size_t)site * 2048 + ccol;
        #pragma unroll
        for (int h = 0; h < 2; ++h) {
            const int c  = c0 + h * 8;
            const int s  = c >> 3;
            const int kk = (c >> 2) & 1;
            const int g  = c & 3;
            const int ub = kk * 16 + 2 * g;
            const float* R = br + s * 1024;
            const float* I = bi + s * 1024;
            float v0 = R[(ub + 0) * 32], v1 = I[(ub + 0) * 32];
            float v2 = R[(ub + 1) * 32], v3 = I[(ub + 1) * 32];
            float v4 = R[(ub + 8) * 32], v5 = I[(ub + 8) * 32];
            float v6 = R[(ub + 9) * 32], v7 = I[(ub + 9) * 32];
            unsigned h0 = cvt_pk_bf16(v0, v1), h1 = cvt_pk_bf16(v2, v3);
            unsigned h2 = cvt_pk_bf16(v4, v5), h3 = cvt_pk_bf16(v6, v7);
            unsigned l0 = cvt_pk_bf16(v0 - lo_f(h0), v1 - hi_f(h0));
            unsigned l1 = cvt_pk_bf16(v2 - lo_f(h1), v3 - hi_f(h1));
            unsigned l2 = cvt_pk_bf16(v4 - lo_f(h2), v5 - hi_f(h2));
            unsigned l3 = cvt_pk_bf16(v6 - lo_f(h3), v7 - hi_f(h3));
            *(u32x4*)&Bf[buf][0][s][kk][g][ccol][0] = (u32x4){h0, h1, h2, h3};
            *(u32x4*)&Bf[buf][1][s][kk][g][ccol][0] = (u32x4){l0, l1, l2, l3};
        }
    };

    if (tid < 32) {
        const int* sp = spin + ((size_t)(blk * 32 + tid)) * 64;
        unsigned a0 = 0, a1 = 0;
        #pragma unroll
        for (int k = 0; k < 32; ++k) a0 |= (unsigned)(sp[k] & 1) << k;
        #pragma unroll
        for (int k = 0; k < 32; ++k) a1 |= (unsigned)(sp[32 + k] & 1) << k;
        smask[tid][0] = a0; smask[tid][1] = a1;
    }
    {
        const int e = tid & 31, jg = tid >> 5;
        const int s0 = spin[((size_t)(blk * 32 + e)) * 64] & 1;
        #pragma unroll
        for (int d = 0; d < 4; ++d) {
            const int j = jg * 4 + d;
            vT[0][2 * j    ][e] = left_r[s0 * 32 + j];
            vT[0][2 * j + 1][e] = left_i[s0 * 32 + j];
        }
    }
    convert(0, 0);
    __syncthreads();

    unsigned em0[4], em1[4];
    #pragma unroll
    for (int r = 0; r < 4; ++r) {
        const int ee = mt * 16 + lg * 4 + r;
        em0[r] = smask[ee][0];
        em1[r] = smask[ee][1];
    }

    #pragma unroll 2
    for (int t = 0; t < 62; ++t) {
        const int b = t & 1;
        float f[16];
        #pragma unroll
        for (int kk = 0; kk < 2; ++kk)
            #pragma unroll
            for (int q = 0; q < 2; ++q)
                #pragma unroll
                for (int r = 0; r < 4; ++r)
                    f[kk * 8 + q * 4 + r] = vT[b][kk * 32 + q * 16 + 4 * lg + r][ve];

        u32x4 Vh[2], Vl[2];
        #pragma unroll
        for (int kk = 0; kk < 2; ++kk)
            #pragma unroll
            for (int q = 0; q < 2; ++q) {
                const float a = f[kk*8+q*4+0], c2 = f[kk*8+q*4+1];
                const float d2 = f[kk*8+q*4+2], e2 = f[kk*8+q*4+3];
                const unsigned h0 = cvt_pk_bf16(a, c2);
                const unsigned h1 = cvt_pk_bf16(d2, e2);
                Vh[kk][q*2+0] = h0;
                Vh[kk][q*2+1] = h1;
                Vl[kk][q*2+0] = cvt_pk_bf16(a - lo_f(h0), c2 - hi_f(h0));
                Vl[kk][q*2+1] = cvt_pk_bf16(d2 - lo_f(h1), e2 - hi_f(h1));
            }

        u32x4 Bh[2][2], Bl[2][2];
        #pragma unroll
        for (int s = 0; s < 2; ++s)
            #pragma unroll
            for (int kk = 0; kk < 2; ++kk) {
                Bh[s][kk] = *(const u32x4*)&Bf[b][0][s][kk][lg][jc][0];
                Bl[s][kk] = *(const u32x4*)&Bf[b][1][s][kk][lg][jc][0];
            }

        if (t < 61) convert(t + 1, b ^ 1);

        f32x4 ar[2] = {{0,0,0,0},{0,0,0,0}};
        f32x4 ai[2] = {{0,0,0,0},{0,0,0,0}};
        #pragma unroll
        for (int kk = 0; kk < 2; ++kk) {
            u32x4 vh, vl;
            #pragma unroll
            for (int q = 0; q < 4; ++q) {
                vh[q] = Vh[kk][q] ^ 0x80000000u;
                vl[q] = Vl[kk][q] ^ 0x80000000u;
            }
            #pragma unroll
            for (int s = 0; s < 2; ++s) {
                ar[s] = MFMA16(vh, Bh[s][kk], ar[s]);
                ar[s] = MFMA16(vh, Bl[s][kk], ar[s]);
                ar[s] = MFMA16(vl, Bh[s][kk], ar[s]);
            }
        }
        #pragma unroll
        for (int kk = 0; kk < 2; ++kk) {
            u32x4 vh, vl;
            #pragma unroll
            for (int q = 0; q < 4; ++q) {
                vh[q] = __builtin_amdgcn_alignbit(Vh[kk][q], Vh[kk][q], 16);
                vl[q] = __builtin_amdgcn_alignbit(Vl[kk][q], Vl[kk][q], 16);
            }
            #pragma unroll
            for (int s = 0; s < 2; ++s) {
                ai[s] = MFMA16(vh, Bh[s][kk], ai[s]);
                ai[s] = MFMA16(vh, Bl[s][kk], ai[s]);
                ai[s] = MFMA16(vl, Bh[s][kk], ai[s]);
            }
        }

        const int bp = t + 1;
        #pragma unroll
        for (int r = 0; r < 4; ++r) {
            const unsigned mw = (bp < 32) ? em0[r] : em1[r];
            const bool sb = (mw >> (bp & 31)) & 1u;
            const int ee = mt * 16 + lg * 4 + r;
            vT[b ^ 1][2 * jc    ][ee] = sb ? ar[1][r] : ar[0][r];
            vT[b ^ 1][2 * jc + 1][ee] = sb ? ai[1][r] : ai[0][r];
        }
        __syncthreads();
    }

    {
        const int e = tid & 31, jg = tid >> 5;
        const unsigned sR = (smask[e][1] >> 31) & 1u;
        const float* Rr = right_r + sR * 32;
        const float* Ri = right_i + sR * 32;
        float pr = 0.f, pi = 0.f;
        #pragma unroll
        for (int d = 0; d < 4; ++d) {
            const int j = jg * 4 + d;
            const float vr = vT[0][2 * j][e], vi = vT[0][2 * j + 1][e];
            pr += vr * Rr[j] - vi * Ri[j];
            pi += vr * Ri[j] + vi * Rr[j];
        }
        red[e][jg] = make_float2(pr, pi);
    }
    __syncthreads();
    if (tid < 32) {
        float2 a = red[tid][0];
        #pragma unroll
        for (int k = 1; k < 8; ++k) { a.x += red[tid][k].x; a.y += red[tid][k].y; }
        out[blk * 32 + tid] = a;
    }
}

extern "C" void kernel_launch(void* const* d_in, const int* in_sizes, int n_in,
                              void* d_out, int out_size, void* d_ws, size_t ws_size,
                              hipStream_t stream)
{
    const int*   spin = (const int*)  d_in[0];
    const float* lr   = (const float*)d_in[1];
    const float* li   = (const float*)d_in[2];
    const float* br   = (const float*)d_in[3];
    const float* bi   = (const float*)d_in[4];
    const float* rr   = (const float*)d_in[5];
    const float* ri   = (const float*)d_in[6];
    float2* out = (float2*)d_out;

    const size_t WS_NEEDED = (size_t)62 * 16384;   // 992 KB
    if (ws_size >= WS_NEEDED) {
        unsigned* ws = (unsigned*)d_ws;
        mps_preconvert<<<dim3(62), dim3(256), 0, stream>>>(br, bi, ws);
        mps_mfma3_kernel<<<dim3(256), dim3(256), 0, stream>>>(spin, lr, li, rr, ri, ws, out);
    } else {
        mps_mfma_kernel_fb<<<dim3(256), dim3(256), 0, stream>>>(spin, lr, li, br, bi, rr, ri, out);
    }
}